// Round 7
// baseline (2756.588 us; speedup 1.0000x reference)
//
#include <hip/hip_runtime.h>

typedef float f4 __attribute__((ext_vector_type(4)));

#define L_SEQ 2048
#define D4    16             // 64 floats = 16 float4 per K/Q row
#define NC4   512            // float4 chunks per output row
#define RAD   128
#define TI    16             // rows per tile
#define NBH   48
#define NTIL  128            // L_SEQ/TI
#define NBLK  (NBH * NTIL)   // 6144

// R3 structure with K staged as packed bf16 (RNE): LDS = 144*128 + 4096
// = 22528 B -> 7 blocks/CU by LDS; __launch_bounds__(256,6) targets >=6
// blocks/CU (24 waves, 75% occupancy vs R3's 50%). More concurrent blocks
// -> phases of different blocks interleave on each CU -> the HBM store
// stream stays fed while others stage/compute.
// bf16 K adds ~0.01 RMS error per dot (<<0.955 threshold); Q stays fp32.

__device__ __forceinline__ unsigned bf16rne(float f) {
    unsigned u = __float_as_uint(f);
    return (u + 0x7FFFu + ((u >> 16) & 1u)) >> 16;   // round-to-nearest-even
}

__global__ __launch_bounds__(256, 6)
void band_fused(const float* __restrict__ Qg, const float* __restrict__ Kg,
                float* __restrict__ outg)
{
    // K rows as 16 8B-units of 4 bf16; unit index swizzled:
    //   U(row,d4) = d4 ^ (((row>>2)&7)<<1) ^ ((row>>5)&1)   -> <=2-way reads
    __shared__ uint2 sK[144 * 16];   // 18432 B
    __shared__ f4    sQ[TI * D4];    //  4096 B, slot = row*16 + (d4 ^ row)

    const int t  = threadIdx.x;
    const int id = blockIdx.x;
    // bijective XCD swizzle (NBLK % 8 == 0)
    const int swz = (id & 7) * (NBLK / 8) + (id >> 3);
    const int bh  = swz >> 7;
    const int i0  = (swz & (NTIL - 1)) * TI;
    const int i04 = i0 >> 2;

    const f4* __restrict__ K4 = reinterpret_cast<const f4*>(Kg) + (size_t)bh * L_SEQ * D4;
    const f4* __restrict__ Q4 = reinterpret_cast<const f4*>(Qg) + (size_t)bh * L_SEQ * D4;
    f4* __restrict__ O4       = reinterpret_cast<f4*>(outg)     + (size_t)bh * L_SEQ * NC4;

    const f4 zero4 = (f4)0.f;

    // ---- zero stores first: no dependencies, starts the HBM write stream
#pragma unroll
    for (int rg = 0; rg < 4; ++rg) {
        int L = i04 + rg - 32; L = L < 0 ? 0 : L;
        int H = i04 + rg + 32; H = H > NC4 - 1 ? NC4 - 1 : H;
        const int rb = (i0 + rg * 4) * NC4;
#pragma unroll
        for (int wz = 0; wz < 8; ++wz) {
            const int ww = wz * 256 + t;
            const int r = ww >> 9, c = ww & (NC4 - 1);
            if (c < L || c > H)
                O4[rb + (size_t)r * NC4 + c] = zero4;
        }
    }

    // ---- stage Q tile (16 rows x 64 fp32), swizzled
    {
        const int row = t >> 4, d4 = t & 15;
        sQ[(row << 4) + (d4 ^ row)] = Q4[(i0 + row) * D4 + d4];
    }

    // ---- stage K phase 0 as bf16: global rows [i0-128, i0+16) (si 0..143)
    const int kb0 = i0 - RAD;
#pragma unroll
    for (int itr = 0; itr < 9; ++itr) {
        const int s  = itr * 256 + t;
        const int si = s >> 4, d4 = s & 15;
        int row = kb0 + si;
        row = row < 0 ? 0 : row;            // clamp; clamped slots never read (guarded)
        const f4 v = K4[(size_t)row * D4 + d4];
        uint2 w;
        w.x = bf16rne(v.x) | (bf16rne(v.y) << 16);
        w.y = bf16rne(v.z) | (bf16rne(v.w) << 16);
        sK[(si << 4) + (d4 ^ ((((si >> 2) & 7) << 1)) ^ ((si >> 5) & 1))] = w;
    }
    __syncthreads();

    // ---- phase 0: items (rg, cb), j4 = i04+rg-32+cb, cb <= 35-rg
    {
        const int rg = t / 36;
        const int cb = t - rg * 36;
        const int j4 = i04 + rg - 32 + cb;
        if (t < 144 && cb <= 35 - rg && j4 >= 0) {
            const int rg4 = rg << 2;
            const int sb  = (rg + cb) << 2;          // staged K row base
            const int x   = ((rg + cb) & 7) << 1;    // ((row>>2)&7)<<1, same for c=0..3
            float acc[4][4];
#pragma unroll
            for (int r = 0; r < 4; ++r)
#pragma unroll
                for (int c = 0; c < 4; ++c) acc[r][c] = 0.f;
#pragma unroll
            for (int d4v = 0; d4v < D4; ++d4v) {
                f4 qv[4];
#pragma unroll
                for (int r = 0; r < 4; ++r) qv[r] = sQ[((rg4 + r) << 4) + (d4v ^ (rg4 + r))];
#pragma unroll
                for (int c = 0; c < 4; ++c) {
                    const int row = sb + c;
                    const uint2 w = sK[(row << 4) + (d4v ^ x ^ ((row >> 5) & 1))];
                    const float k0 = __uint_as_float(w.x << 16);
                    const float k1 = __uint_as_float(w.x & 0xffff0000u);
                    const float k2 = __uint_as_float(w.y << 16);
                    const float k3 = __uint_as_float(w.y & 0xffff0000u);
#pragma unroll
                    for (int r = 0; r < 4; ++r)
                        acc[r][c] += qv[r].x * k0 + qv[r].y * k1
                                   + qv[r].z * k2 + qv[r].w * k3;
                }
            }
            const int c0 = j4 << 2;
#pragma unroll
            for (int r = 0; r < 4; ++r) {
                const int i = i0 + rg4 + r;
                f4 v;
                v.x = ((unsigned)(i - (c0 + 0) + RAD) <= 2u * RAD) ? acc[r][0] : 0.f;
                v.y = ((unsigned)(i - (c0 + 1) + RAD) <= 2u * RAD) ? acc[r][1] : 0.f;
                v.z = ((unsigned)(i - (c0 + 2) + RAD) <= 2u * RAD) ? acc[r][2] : 0.f;
                v.w = ((unsigned)(i - (c0 + 3) + RAD) <= 2u * RAD) ? acc[r][3] : 0.f;
                O4[(size_t)i * NC4 + j4] = v;
            }
        }
    }
    __syncthreads();   // phase-0 LDS reads done before overwrite

    // ---- stage K phase 1 as bf16: global rows [i0+16, i0+144) (si 0..127)
    const int kb1 = i0 + TI;
#pragma unroll
    for (int itr = 0; itr < 8; ++itr) {
        const int s  = itr * 256 + t;
        const int si = s >> 4, d4 = s & 15;
        int row = kb1 + si;
        row = row > L_SEQ - 1 ? L_SEQ - 1 : row;   // clamp; never read (guarded)
        const f4 v = K4[(size_t)row * D4 + d4];
        uint2 w;
        w.x = bf16rne(v.x) | (bf16rne(v.y) << 16);
        w.y = bf16rne(v.z) | (bf16rne(v.w) << 16);
        sK[(si << 4) + (d4 ^ ((((si >> 2) & 7) << 1)) ^ ((si >> 5) & 1))] = w;
    }
    __syncthreads();

    // ---- phase 1: items (rg, cb), j4 = i04+4+cb, cb <= 28+rg
    {
        const int rg = t >> 5;
        const int cb = t & 31;
        const int j4 = i04 + 4 + cb;
        if (t < 128 && cb <= 28 + rg && j4 <= NC4 - 1) {
            const int rg4 = rg << 2;
            const int sb  = cb << 2;
            const int x   = (cb & 7) << 1;
            float acc[4][4];
#pragma unroll
            for (int r = 0; r < 4; ++r)
#pragma unroll
                for (int c = 0; c < 4; ++c) acc[r][c] = 0.f;
#pragma unroll
            for (int d4v = 0; d4v < D4; ++d4v) {
                f4 qv[4];
#pragma unroll
                for (int r = 0; r < 4; ++r) qv[r] = sQ[((rg4 + r) << 4) + (d4v ^ (rg4 + r))];
#pragma unroll
                for (int c = 0; c < 4; ++c) {
                    const int row = sb + c;
                    const uint2 w = sK[(row << 4) + (d4v ^ x ^ ((row >> 5) & 1))];
                    const float k0 = __uint_as_float(w.x << 16);
                    const float k1 = __uint_as_float(w.x & 0xffff0000u);
                    const float k2 = __uint_as_float(w.y << 16);
                    const float k3 = __uint_as_float(w.y & 0xffff0000u);
#pragma unroll
                    for (int r = 0; r < 4; ++r)
                        acc[r][c] += qv[r].x * k0 + qv[r].y * k1
                                   + qv[r].z * k2 + qv[r].w * k3;
                }
            }
            const int c0 = j4 << 2;
#pragma unroll
            for (int r = 0; r < 4; ++r) {
                const int i = i0 + rg4 + r;
                f4 v;
                v.x = ((unsigned)(i - (c0 + 0) + RAD) <= 2u * RAD) ? acc[r][0] : 0.f;
                v.y = ((unsigned)(i - (c0 + 1) + RAD) <= 2u * RAD) ? acc[r][1] : 0.f;
                v.z = ((unsigned)(i - (c0 + 2) + RAD) <= 2u * RAD) ? acc[r][2] : 0.f;
                v.w = ((unsigned)(i - (c0 + 3) + RAD) <= 2u * RAD) ? acc[r][3] : 0.f;
                O4[(size_t)i * NC4 + j4] = v;
            }
        }
    }
}

extern "C" void kernel_launch(void* const* d_in, const int* in_sizes, int n_in,
                              void* d_out, int out_size, void* d_ws, size_t ws_size,
                              hipStream_t stream) {
    const float* Q = (const float*)d_in[0];
    const float* K = (const float*)d_in[1];
    float* out = (float*)d_out;
    band_fused<<<NBLK, 256, 0, stream>>>(Q, K, out);
}

// Round 8
// 214.425 us; speedup vs baseline: 12.8557x; 12.8557x over previous
//
#include <hip/hip_runtime.h>

typedef float f4 __attribute__((ext_vector_type(4)));

#define L_SEQ 2048
#define D4    16             // 64 floats = 16 float4 per K/Q row
#define NC4   512            // float4 chunks per output row
#define RAD   128
#define TI    16             // rows per tile
#define NBH   48
#define NTIL  128            // L_SEQ/TI
#define NBLK  (NBH * NTIL)   // 6144

// R3 structure, occupancy-engineered: bf16 K in LDS (22528 B total) and
// 2-row x 4-col work items (acc=8, qv=8 regs) with unroll-4 on the d4 loop
// keep VGPR well under the 84 cap of __launch_bounds__(256,6)
// -> 6 blocks/CU (24 waves, 75% occupancy) vs R3's 4 blocks (50%).
// R7's 12x regression was reg-spill (VGPR pinned to 40 + full unroll);
// this build leaves ~30 VGPRs of headroom.

__device__ __forceinline__ unsigned bf16rne(float f) {
    unsigned u = __float_as_uint(f);
    return (u + 0x7FFFu + ((u >> 16) & 1u)) >> 16;   // round-to-nearest-even
}

__global__ __launch_bounds__(256, 6)
void band_fused(const float* __restrict__ Qg, const float* __restrict__ Kg,
                float* __restrict__ outg)
{
    // K rows as 16 8B-units of 4 bf16; unit index swizzled:
    //   U(row,d4) = d4 ^ (((row>>2)&7)<<1) ^ ((row>>5)&1)  -> <=2-way reads
    __shared__ uint2 sK[144 * 16];   // 18432 B
    __shared__ f4    sQ[TI * D4];    //  4096 B, slot = row*16 + (d4 ^ row)

    const int t  = threadIdx.x;
    const int id = blockIdx.x;
    // bijective XCD swizzle (NBLK % 8 == 0)
    const int swz = (id & 7) * (NBLK / 8) + (id >> 3);
    const int bh  = swz >> 7;
    const int i0  = (swz & (NTIL - 1)) * TI;
    const int i04 = i0 >> 2;

    const f4* __restrict__ K4 = reinterpret_cast<const f4*>(Kg) + (size_t)bh * L_SEQ * D4;
    const f4* __restrict__ Q4 = reinterpret_cast<const f4*>(Qg) + (size_t)bh * L_SEQ * D4;
    f4* __restrict__ O4       = reinterpret_cast<f4*>(outg)     + (size_t)bh * L_SEQ * NC4;

    const f4 zero4 = (f4)0.f;

    // ---- zero stores first: no input dependency, starts the HBM write stream
#pragma unroll
    for (int rg = 0; rg < 4; ++rg) {
        int L = i04 + rg - 32; L = L < 0 ? 0 : L;
        int H = i04 + rg + 32; H = H > NC4 - 1 ? NC4 - 1 : H;
        const int rb = (i0 + rg * 4) * NC4;
#pragma unroll
        for (int wz = 0; wz < 8; ++wz) {
            const int ww = wz * 256 + t;
            const int r = ww >> 9, c = ww & (NC4 - 1);
            if (c < L || c > H)
                O4[rb + (size_t)r * NC4 + c] = zero4;
        }
    }

    // ---- stage Q tile (16 rows x 64 fp32), swizzled
    {
        const int row = t >> 4, d4 = t & 15;
        sQ[(row << 4) + (d4 ^ row)] = Q4[(i0 + row) * D4 + d4];
    }

    // shared compute body: 2 rows (local rl0, rl0+1) x 4 cols (chunk j4),
    // K staged rows sb..sb+3, x = ((sb>>2)&7)<<1 precomputed by caller.
    auto body = [&](int rl0, int sb, int x, int j4) {
        float acc[2][4];
#pragma unroll
        for (int r = 0; r < 2; ++r)
#pragma unroll
            for (int c = 0; c < 4; ++c) acc[r][c] = 0.f;
#pragma unroll 4
        for (int d4v = 0; d4v < D4; ++d4v) {
            const f4 q0 = sQ[((rl0    ) << 4) + (d4v ^ (rl0    ))];
            const f4 q1 = sQ[((rl0 + 1) << 4) + (d4v ^ (rl0 + 1))];
#pragma unroll
            for (int c = 0; c < 4; ++c) {
                const int row = sb + c;
                const uint2 w = sK[(row << 4) + (d4v ^ x ^ ((row >> 5) & 1))];
                const float k0 = __uint_as_float(w.x << 16);
                const float k1 = __uint_as_float(w.x & 0xffff0000u);
                const float k2 = __uint_as_float(w.y << 16);
                const float k3 = __uint_as_float(w.y & 0xffff0000u);
                acc[0][c] += q0.x * k0 + q0.y * k1 + q0.z * k2 + q0.w * k3;
                acc[1][c] += q1.x * k0 + q1.y * k1 + q1.z * k2 + q1.w * k3;
            }
        }
        const int c0 = j4 << 2;
#pragma unroll
        for (int r = 0; r < 2; ++r) {
            const int i = i0 + rl0 + r;
            f4 v;
            v.x = ((unsigned)(i - (c0 + 0) + RAD) <= 2u * RAD) ? acc[r][0] : 0.f;
            v.y = ((unsigned)(i - (c0 + 1) + RAD) <= 2u * RAD) ? acc[r][1] : 0.f;
            v.z = ((unsigned)(i - (c0 + 2) + RAD) <= 2u * RAD) ? acc[r][2] : 0.f;
            v.w = ((unsigned)(i - (c0 + 3) + RAD) <= 2u * RAD) ? acc[r][3] : 0.f;
            O4[(size_t)i * NC4 + j4] = v;
        }
    };

    // ---- stage K phase 0 as bf16: global rows [i0-128, i0+16) (si 0..143)
    const int kb0 = i0 - RAD;
#pragma unroll
    for (int itr = 0; itr < 9; ++itr) {
        const int s  = itr * 256 + t;
        const int si = s >> 4, d4 = s & 15;
        int row = kb0 + si;
        row = row < 0 ? 0 : row;            // clamp; clamped slots never read (guarded)
        const f4 v = K4[(size_t)row * D4 + d4];
        uint2 w;
        w.x = bf16rne(v.x) | (bf16rne(v.y) << 16);
        w.y = bf16rne(v.z) | (bf16rne(v.w) << 16);
        sK[(si << 4) + (d4 ^ ((((si >> 2) & 7) << 1)) ^ ((si >> 5) & 1))] = w;
    }
    __syncthreads();

    // ---- phase 0: 288 half-items (rg2, cb): rg = rg2>>1, h = rg2&1,
    // j4 = i04+rg-32+cb, valid iff cb <= 35-rg && j4 >= 0
    auto item0 = [&](int rg2, int cb) {
        const int rg = rg2 >> 1, h = rg2 & 1;
        const int j4 = i04 + rg - 32 + cb;
        if (cb <= 35 - rg && j4 >= 0)
            body((rg << 2) + (h << 1), (rg + cb) << 2, ((rg + cb) & 7) << 1, j4);
    };
    {
        const int rg2 = t / 36;
        item0(rg2, t - rg2 * 36);
        if (t < 32) item0(7, t + 4);       // items 256..287
    }
    __syncthreads();   // phase-0 LDS reads done before overwrite

    // ---- stage K phase 1 as bf16: global rows [i0+16, i0+144) (si 0..127)
    const int kb1 = i0 + TI;
#pragma unroll
    for (int itr = 0; itr < 8; ++itr) {
        const int s  = itr * 256 + t;
        const int si = s >> 4, d4 = s & 15;
        int row = kb1 + si;
        row = row > L_SEQ - 1 ? L_SEQ - 1 : row;   // clamp; never read (guarded)
        const f4 v = K4[(size_t)row * D4 + d4];
        uint2 w;
        w.x = bf16rne(v.x) | (bf16rne(v.y) << 16);
        w.y = bf16rne(v.z) | (bf16rne(v.w) << 16);
        sK[(si << 4) + (d4 ^ ((((si >> 2) & 7) << 1)) ^ ((si >> 5) & 1))] = w;
    }
    __syncthreads();

    // ---- phase 1: 256 half-items (rg2 = t>>5, cb = t&31):
    // j4 = i04+4+cb, valid iff cb <= 28+rg && j4 <= 511
    {
        const int rg2 = t >> 5, cb = t & 31;
        const int rg = rg2 >> 1, h = rg2 & 1;
        const int j4 = i04 + 4 + cb;
        if (cb <= 28 + rg && j4 <= NC4 - 1)
            body((rg << 2) + (h << 1), cb << 2, (cb & 7) << 1, j4);
    }
}

extern "C" void kernel_launch(void* const* d_in, const int* in_sizes, int n_in,
                              void* d_out, int out_size, void* d_ws, size_t ws_size,
                              hipStream_t stream) {
    const float* Q = (const float*)d_in[0];
    const float* K = (const float*)d_in[1];
    float* out = (float*)d_out;
    band_fused<<<NBLK, 256, 0, stream>>>(Q, K, out);
}

// Round 9
// 200.528 us; speedup vs baseline: 13.7466x; 1.0693x over previous
//
#include <hip/hip_runtime.h>

typedef float f4 __attribute__((ext_vector_type(4)));

#define L_SEQ 2048
#define D4    16             // 64 floats = 16 float4 per K/Q row
#define NC4   512            // float4 chunks per output row
#define RAD   128
#define TI    32             // rows per tile
#define NBH   48
#define NTIL  64             // L_SEQ/TI
#define NBLK  (NBH * NTIL)   // 3072
#define KROWS 288            // staged K rows: [i0-128, i0+160)
#define WIN   68             // per-rowgroup window width in chunks
#define ZN    (NC4 - WIN)    // 444 zero chunks per row

// Wave-specialized block: 512 threads on one (b,h) x 32-row tile.
//   waves 0-3: band compute (LDS-staged bf16 K + fp32 Q, 2rx4c items)
//   waves 4-7: pure zero-streaming of the window complement (fill-kernel
//              clone; stalls on the store queue by design, keeping the HBM
//              write pipe continuously fed while compute waves own the VALU)
// Window contract: rowgroup g (4 rows) has window [w, w+68), w =
// clamp(i04+g-32, 0, 444); band [a-32,a+32] always inside; compute waves
// write the window (band-masked zeros for the <=3 spare chunks), zero waves
// write the exact complement. LDS = 36864+8192 = 45056 B -> 3 blocks/CU.

__device__ __forceinline__ unsigned bf16rne(float f) {
    unsigned u = __float_as_uint(f);
    return (u + 0x7FFFu + ((u >> 16) & 1u)) >> 16;   // round-to-nearest-even
}

__global__ __launch_bounds__(512, 6)
void band_ws(const float* __restrict__ Qg, const float* __restrict__ Kg,
             float* __restrict__ outg)
{
    // K rows as 16 8B-units of 4 bf16, unit swizzled:
    //   U(row,d4) = d4 ^ (((row>>2)&7)<<1) ^ ((row>>5)&1)  -> full-bank spread
    __shared__ uint2 sK[KROWS * 16];   // 36864 B
    __shared__ f4    sQ[TI * D4];      //  8192 B

    const int t  = threadIdx.x;
    const int id = blockIdx.x;
    // bijective XCD swizzle (NBLK % 8 == 0)
    const int swz = (id & 7) * (NBLK / 8) + (id >> 3);
    const int bh  = swz >> 6;
    const int i0  = (swz & (NTIL - 1)) * TI;
    const int i04 = i0 >> 2;

    const f4* __restrict__ K4 = reinterpret_cast<const f4*>(Kg) + (size_t)bh * L_SEQ * D4;
    const f4* __restrict__ Q4 = reinterpret_cast<const f4*>(Qg) + (size_t)bh * L_SEQ * D4;
    f4* __restrict__ O4       = reinterpret_cast<f4*>(outg)     + (size_t)bh * L_SEQ * NC4;

    const int kbase = i0 - RAD;

    // ---- all 512 threads stage: K 288 rows (9 units each), Q 32 rows (1 each)
#pragma unroll
    for (int itr = 0; itr < 9; ++itr) {
        const int s  = itr * 512 + t;
        const int si = s >> 4, d4 = s & 15;
        int row = kbase + si;
        row = row < 0 ? 0 : (row > L_SEQ - 1 ? L_SEQ - 1 : row);  // clamp; masked at store
        const f4 v = K4[(size_t)row * D4 + d4];
        uint2 w;
        w.x = bf16rne(v.x) | (bf16rne(v.y) << 16);
        w.y = bf16rne(v.z) | (bf16rne(v.w) << 16);
        sK[(si << 4) + (d4 ^ ((((si >> 2) & 7) << 1)) ^ ((si >> 5) & 1))] = w;
    }
    {
        const int row = t >> 4, d4 = t & 15;     // t in [0,512) covers 32x16 exactly
        sQ[(row << 4) + (d4 ^ (row & 15))] = Q4[(i0 + row) * D4 + d4];
    }
    __syncthreads();

    if (t < 256) {
        // ================= compute waves =================
        // 1088 items = 16 rowpairs x 68 window chunks; item m: rp=m/68, c=m%68
#pragma unroll 1
        for (int k = 0; k < 5; ++k) {
            const int m = t + (k << 8);
            if (m < 1088) {
                const int rp = m / 68;
                const int c  = m - rp * 68;
                const int g  = rp >> 1;
                int w = i04 + g - 32; w = w < 0 ? 0 : (w > ZN ? ZN : w);
                const int j4  = w + c;
                const int sb  = (j4 << 2) - kbase;          // staged K row base (mult of 4)
                const int X   = ((((sb >> 2) & 7) << 1)) ^ ((sb >> 5) & 1);
                const int rl0 = rp << 1;

                float acc[2][4];
#pragma unroll
                for (int r = 0; r < 2; ++r)
#pragma unroll
                    for (int cc = 0; cc < 4; ++cc) acc[r][cc] = 0.f;
#pragma unroll 4
                for (int d4v = 0; d4v < D4; ++d4v) {
                    const f4 q0 = sQ[((rl0    ) << 4) + (d4v ^ ((rl0    ) & 15))];
                    const f4 q1 = sQ[((rl0 + 1) << 4) + (d4v ^ ((rl0 + 1) & 15))];
                    const int du = d4v ^ X;
#pragma unroll
                    for (int cc = 0; cc < 4; ++cc) {
                        const uint2 wv = sK[((sb + cc) << 4) + du];
                        const float k0 = __uint_as_float(wv.x << 16);
                        const float k1 = __uint_as_float(wv.x & 0xffff0000u);
                        const float k2 = __uint_as_float(wv.y << 16);
                        const float k3 = __uint_as_float(wv.y & 0xffff0000u);
                        acc[0][cc] += q0.x * k0 + q0.y * k1 + q0.z * k2 + q0.w * k3;
                        acc[1][cc] += q1.x * k0 + q1.y * k1 + q1.z * k2 + q1.w * k3;
                    }
                }
                const int c0 = j4 << 2;
#pragma unroll
                for (int r = 0; r < 2; ++r) {
                    const int i = i0 + rl0 + r;
                    f4 v;
                    v.x = ((unsigned)(i - (c0 + 0) + RAD) <= 2u * RAD) ? acc[r][0] : 0.f;
                    v.y = ((unsigned)(i - (c0 + 1) + RAD) <= 2u * RAD) ? acc[r][1] : 0.f;
                    v.z = ((unsigned)(i - (c0 + 2) + RAD) <= 2u * RAD) ? acc[r][2] : 0.f;
                    v.w = ((unsigned)(i - (c0 + 3) + RAD) <= 2u * RAD) ? acc[r][3] : 0.f;
                    O4[(size_t)i * NC4 + j4] = v;
                }
            }
        }
    } else {
        // ================= zero-stream waves =================
        const int tz = t - 256;
        const f4 zero4 = (f4)0.f;
#pragma unroll 4
        for (int r = 0; r < TI; ++r) {
            const int i = i0 + r;
            int w = i04 + (r >> 2) - 32; w = w < 0 ? 0 : (w > ZN ? ZN : w);
            f4* rowp = O4 + (size_t)i * NC4;
            const int jA = tz < w ? tz : tz + WIN;     // tz in [0,256) < ZN always
            rowp[jA] = zero4;
            const int z2 = tz + 256;
            if (z2 < ZN) {
                const int jB = z2 < w ? z2 : z2 + WIN;
                rowp[jB] = zero4;
            }
        }
    }
}

extern "C" void kernel_launch(void* const* d_in, const int* in_sizes, int n_in,
                              void* d_out, int out_size, void* d_ws, size_t ws_size,
                              hipStream_t stream) {
    const float* Q = (const float*)d_in[0];
    const float* K = (const float*)d_in[1];
    float* out = (float*)d_out;
    band_ws<<<NBLK, 512, 0, stream>>>(Q, K, out);
}